// Round 11
// baseline (407.546 us; speedup 1.0000x reference)
//
#include <hip/hip_runtime.h>
#include <hip/hip_bf16.h>

// DigitCaps dynamic routing. Output fp32.
// R24: single cooperative mega-kernel with MANUAL grid barriers built from
// the session-proven protocol (WT stores + vmcnt(0) + monotonic arrive ctr +
// relaxed-agent spin + acquire-fence-at-idle). R17 showed grid.sync() costs
// ~80us (wb+inv per block); our barrier does inv only, when all blocks are
// parked, and all inter-phase data is write-through (nothing dirty).
// Phases = R20-proven bodies, grid-strided (R17 proved grid-stride math).
// 10 barriers. Bounded spin (bug -> wrong answer, not hang). Fallback:
// 12-dispatch chain of the same phase wrappers if coop launch errors.
#define B 512
#define IC 1152
#define QD 8
#define OD 10
#define PD 16
#define KD (IC * QD)       // 9216
#define NKB (KD / 32)      // 288 K32 blocks
#define NCS 12             // K-chunks for s GEMM (4 waves x 6 steps each)
#define SOP (B * OD * PD)  // 81920
#define IO (IC * OD)       // 11520
#define TPX ((B / 64) * (KD / 64))  // 1152 transpose tiles
#define NBTARGET 576
#define SMEMB 43008        // 4*16*168 floats (sgemm reduce buf)

typedef short bf16x8 __attribute__((ext_vector_type(8)));
typedef short bf16x4 __attribute__((ext_vector_type(4)));
typedef float f32x4 __attribute__((ext_vector_type(4)));

__device__ __forceinline__ short f2bf(float f) {
  union { float f; unsigned u; } x;
  x.f = f;
  unsigned r = x.u + 0x7FFFu + ((x.u >> 16) & 1u);  // RNE to bf16
  return (short)(r >> 16);
}
__device__ __forceinline__ float alf(const float* p) {
  return __hip_atomic_load(p, __ATOMIC_RELAXED, __HIP_MEMORY_SCOPE_AGENT);
}
__device__ __forceinline__ void stf(float* p, float v) {
  __hip_atomic_store(p, v, __ATOMIC_RELAXED, __HIP_MEMORY_SCOPE_AGENT);
}
__device__ __forceinline__ void st64(void* p, unsigned long long v) {
  __hip_atomic_store((unsigned long long*)p, v, __ATOMIC_RELAXED,
                     __HIP_MEMORY_SCOPE_AGENT);
}
__device__ __forceinline__ void st32(void* p, unsigned v) {
  __hip_atomic_store((unsigned*)p, v, __ATOMIC_RELAXED, __HIP_MEMORY_SCOPE_AGENT);
}
__device__ __forceinline__ unsigned long long ld64s(const short* p) {
  unsigned long long v;
  __builtin_memcpy(&v, p, 8);
  return v;
}

// manual grid barrier: drain WT stores, arrive, spin to nb*k, inv-at-idle.
__device__ __forceinline__ void gridbar(int* bc, int k) {
  asm volatile("s_waitcnt vmcnt(0)" ::: "memory");
  __syncthreads();
  if (threadIdx.x == 0) {
    __hip_atomic_fetch_add(bc, 1, __ATOMIC_RELAXED, __HIP_MEMORY_SCOPE_AGENT);
    const int target = (int)gridDim.x * k;
    for (long it = 0; it < 10000000L; ++it) {
      if (__hip_atomic_load(bc, __ATOMIC_RELAXED, __HIP_MEMORY_SCOPE_AGENT) >= target)
        break;
    }
  }
  __syncthreads();
  __builtin_amdgcn_fence(__ATOMIC_ACQUIRE, "agent");  // inv while idle; WT data safe
}

// Bs element: 4 i-quads x (o,p) -> 32 shorts, WT-stored as 8x8B.
__device__ __forceinline__ void bs_store(const float* __restrict__ W,
                                         short* __restrict__ Bs, int t,
                                         const float cw[4]) {
  const int kb = t / 160, n = t % 160;
  const int o = n >> 4, p = n & 15;
  union { short s[32]; unsigned long long u[8]; } ov;
#pragma unroll
  for (int q = 0; q < 4; ++q) {
    const int i = kb * 4 + q;
    const float ci = cw[q];
    const float4* wp = (const float4*)(W + (((size_t)i * OD + o) * PD + p) * QD);
    const float4 w0 = wp[0], w1 = wp[1];
    ov.s[q * 8 + 0] = f2bf(ci * w0.x); ov.s[q * 8 + 1] = f2bf(ci * w0.y);
    ov.s[q * 8 + 2] = f2bf(ci * w0.z); ov.s[q * 8 + 3] = f2bf(ci * w0.w);
    ov.s[q * 8 + 4] = f2bf(ci * w1.x); ov.s[q * 8 + 5] = f2bf(ci * w1.y);
    ov.s[q * 8 + 6] = f2bf(ci * w1.z); ov.s[q * 8 + 7] = f2bf(ci * w1.w);
  }
  unsigned long long* dst = (unsigned long long*)(Bs + (size_t)t * 32);
#pragma unroll
  for (int j = 0; j < 8; ++j) st64(dst + j, ov.u[j]);
}

// ---- phase: prep (xB/xT transpose + uniform Bs; all WT) --------------------
__device__ void phase_prep(int bid, int nb, int tid, const float* __restrict__ x,
                           const float* __restrict__ W, short* __restrict__ Bs,
                           short* __restrict__ xB, short* __restrict__ xT,
                           char* smem) {
  short* tl = (short*)smem;  // 64*72 shorts
  for (int vb = bid; vb < TPX; vb += nb) {
    const int bt = vb / (KD / 64), qt = vb % (KD / 64);
    const int b0 = bt * 64, c0 = qt * 64;
    const int row0 = tid >> 4, col4 = (tid & 15) * 4;
#pragma unroll
    for (int j = 0; j < 4; ++j) {
      const int row = row0 + j * 16;
      const float4 v = *(const float4*)(x + (size_t)(b0 + row) * KD + c0 + col4);
      union { bf16x4 v; unsigned long long u; } ov;
      ov.v[0] = f2bf(v.x); ov.v[1] = f2bf(v.y);
      ov.v[2] = f2bf(v.z); ov.v[3] = f2bf(v.w);
      st64(xB + (size_t)(b0 + row) * KD + c0 + col4, ov.u);
      tl[(col4 + 0) * 72 + row] = ov.v[0];
      tl[(col4 + 1) * 72 + row] = ov.v[1];
      tl[(col4 + 2) * 72 + row] = ov.v[2];
      tl[(col4 + 3) * 72 + row] = ov.v[3];
    }
    __syncthreads();
    const int iq = tid & 63, seg = tid >> 6;  // 16 b per (iq,seg)
    const short* src = tl + iq * 72 + seg * 16;
    short* dst = xT + (size_t)(c0 + iq) * B + b0 + seg * 16;
    st64(dst + 0, ld64s(src + 0));
    st64(dst + 4, ld64s(src + 4));
    st64(dst + 8, ld64s(src + 8));
    st64(dst + 12, ld64s(src + 12));
    __syncthreads();
  }
  const float cw[4] = {1.0f / IC, 1.0f / IC, 1.0f / IC, 1.0f / IC};
  for (int vb = bid; vb < 180; vb += nb) bs_store(W, Bs, vb * 256 + tid, cw);
}

// ---- phase: sgemm (R20 geometry: 384 units, 16-row x fullN, 4-wave Ksplit) -
__device__ void phase_sgemm(int bid, int nb, int tid, const short* __restrict__ xB,
                            const short* __restrict__ Bs, float* __restrict__ s_part,
                            char* smem) {
  float (*sbuf)[16][168] = (float (*)[16][168])smem;
  const int wave = tid >> 6, lane = tid & 63;
  const int ln = lane & 15, quad = lane >> 4;
  for (int vb = bid; vb < 32 * NCS; vb += nb) {
    const int cz = vb % NCS, mb = vb / NCS;
    const int m0 = mb * 16;
    const int czw = cz * 4 + wave;  // 0..47, 6 K32-steps each
    f32x4 acc[10] = {};
    const short* arow = xB + (size_t)(m0 + ln) * KD + quad * 8;
#pragma unroll
    for (int step = 0; step < 6; ++step) {
      const int kb = czw * 6 + step;
      const bf16x8 af = *(const bf16x8*)(arow + (size_t)kb * 32);
      const short* bp = Bs + (size_t)kb * 5120 + ln * 32 + quad * 8;
#pragma unroll
      for (int nt = 0; nt < 10; ++nt) {
        const bf16x8 bf = *(const bf16x8*)(bp + nt * 512);
        acc[nt] = __builtin_amdgcn_mfma_f32_16x16x32_bf16(af, bf, acc[nt], 0, 0, 0);
      }
    }
#pragma unroll
    for (int nt = 0; nt < 10; ++nt)
#pragma unroll
      for (int r = 0; r < 4; ++r)
        sbuf[wave][quad * 4 + r][nt * 16 + ln] = acc[nt][r];
    __syncthreads();
#pragma unroll
    for (int j = 0; j < 10; ++j) {
      const int e = tid + j * 256;  // 0..2559
      const int row = e / 160, col = e - row * 160;
      const float v = sbuf[0][row][col] + sbuf[1][row][col] +
                      sbuf[2][row][col] + sbuf[3][row][col];
      stf(&s_part[((size_t)cz * B + m0 + row) * 160 + col], v);
    }
    __syncthreads();
  }
}

// ---- phase: squash (sum 12 partials via bypass loads, /esum, squash) -------
__device__ void phase_squash(int bid, int nb, int tid, const float* __restrict__ s_part,
                             const float* __restrict__ esum_in, short* __restrict__ vB,
                             float* __restrict__ out, int write_out, char* smem) {
  float* einv = (float*)smem;
  if (tid < OD) einv[tid] = 1.f / alf(esum_in + tid);
  __syncthreads();
  for (int u = bid * 256 + tid; u < 40960; u += nb * 256) {
    const int bp = u / 160, n = u - bp * 160, b0 = bp * 2, o = n >> 4;
    float s0 = 0.f, s1 = 0.f;
#pragma unroll
    for (int c2 = 0; c2 < NCS; ++c2) {
      s0 += alf(&s_part[((size_t)c2 * B + b0) * 160 + n]);
      s1 += alf(&s_part[((size_t)c2 * B + b0 + 1) * 160 + n]);
    }
    s0 *= einv[o]; s1 *= einv[o];
    float sq0 = s0 * s0, sq1 = s1 * s1;
#pragma unroll
    for (int m = 1; m < 16; m <<= 1) {
      sq0 += __shfl_xor(sq0, m, 16);
      sq1 += __shfl_xor(sq1, m, 16);
    }
    const float v0 = s0 * (sq0 / ((1.f + sq0) * sqrtf(sq0 + 1e-8f)));
    const float v1 = s1 * (sq1 / ((1.f + sq1) * sqrtf(sq1 + 1e-8f)));
    if (write_out) {
      out[(size_t)b0 * 160 + n] = v0;
      out[(size_t)(b0 + 1) * 160 + n] = v1;
    } else {
      const unsigned pack =
          (unsigned)(unsigned short)f2bf(v0) | ((unsigned)(unsigned short)f2bf(v1) << 16);
      st32(vB + ((size_t)(b0 >> 5) * 160 + n) * 32 + (b0 & 31), pack);
    }
  }
  __syncthreads();
}

// ---- phase: agg (agreement MFMA; bijT atomics, drained by next gridbar) ----
__device__ void phase_agg(int bid, int nb, int tid, const short* __restrict__ xT,
                          const float* __restrict__ W, const short* __restrict__ vB,
                          float* __restrict__ bijT) {
  const int mt = tid >> 6, lane = tid & 63;
  const int ln = lane & 15, quad = lane >> 4;
  for (int vb = bid; vb < 576; vb += nb) {
    const int ig8 = vb % 144, kq = vb / 144;
    f32x4 acc[10] = {};
    const short* arow = xT + (size_t)(ig8 * 64 + mt * 16 + ln) * B + kq * 128 + quad * 8;
#pragma unroll
    for (int kb = 0; kb < 4; ++kb) {
      const bf16x8 af = *(const bf16x8*)(arow + kb * 32);
      const short* bp = vB + ((size_t)(kq * 4 + kb) * 160 + ln) * 32 + quad * 8;
#pragma unroll
      for (int nt = 0; nt < 10; ++nt) {
        const bf16x8 bf = *(const bf16x8*)(bp + nt * 512);
        acc[nt] = __builtin_amdgcn_mfma_f32_16x16x32_bf16(af, bf, acc[nt], 0, 0, 0);
      }
    }
    const int i = ig8 * 8 + mt * 2 + (quad >> 1);
    const int qb = (quad & 1) * 4;
#pragma unroll
    for (int nt = 0; nt < 10; ++nt) {
      const float4 wv = *(const float4*)(W + (((size_t)i * OD + nt) * PD + ln) * QD + qb);
      float pa = acc[nt][0] * wv.x + acc[nt][1] * wv.y + acc[nt][2] * wv.z + acc[nt][3] * wv.w;
      pa += __shfl_xor(pa, 1); pa += __shfl_xor(pa, 2); pa += __shfl_xor(pa, 4);
      pa += __shfl_xor(pa, 8); pa += __shfl_xor(pa, 16);
      if ((lane & 31) == 0)
        atomicAdd(&bijT[(size_t)nt * IC + i], pa * (1.0f / (float)B));
    }
  }
}

// ---- phase: rebuild (Bs = exp(bij)*W unnorm; esum contribution) ------------
__device__ void phase_rebuild(int bid, int nb, int tid, const float* __restrict__ W,
                              const float* __restrict__ bijT, short* __restrict__ Bs,
                              float* __restrict__ esumOut, char* smem) {
  float (*eL)[OD] = (float (*)[OD])smem;
  for (int vb = bid; vb < 144; vb += nb) {
    const int ig8 = vb;
    if (tid < 8 * OD) {
      const int il = tid / OD, o = tid - il * OD;
      eL[il][o] = __expf(alf(&bijT[(size_t)o * IC + ig8 * 8 + il]));
    }
    __syncthreads();
    if (tid < OD) {
      float s = 0.f;
#pragma unroll
      for (int il = 0; il < 8; ++il) s += eL[il][tid];
      atomicAdd(&esumOut[tid], s);
    }
    for (int vbi = tid; vbi < 320; vbi += 256) {
      const int kbl = vbi / 160, n = vbi - kbl * 160;
      const int kb = ig8 * 2 + kbl;
      const float cw[4] = {eL[kbl * 4 + 0][n >> 4], eL[kbl * 4 + 1][n >> 4],
                           eL[kbl * 4 + 2][n >> 4], eL[kbl * 4 + 3][n >> 4]};
      bs_store(W, Bs, kb * 160 + n, cw);
    }
    __syncthreads();
  }
}

// ---- init: zero bijT + barrier ctr, preset esum ----------------------------
__global__ __launch_bounds__(256) void init_kernel(float* __restrict__ bijT,
                                                   float* __restrict__ esum,
                                                   int* __restrict__ bc) {
  const int g = blockIdx.x * 256 + threadIdx.x;
  if (g < IO) bijT[g] = 0.f;
  if (g < 48) esum[g] = (g < 16) ? (float)IC : 0.f;
  if (g == 0) *bc = 0;
}

// ---- mega: all phases, manual barriers -------------------------------------
__global__ __launch_bounds__(256) void mega_kernel(const float* __restrict__ x,
                                                   const float* __restrict__ W,
                                                   float* __restrict__ out,
                                                   float* __restrict__ s_part,
                                                   float* __restrict__ bijT,
                                                   float* __restrict__ esum,
                                                   int* __restrict__ bc,
                                                   short* __restrict__ vB,
                                                   short* __restrict__ Bs,
                                                   short* __restrict__ xB,
                                                   short* __restrict__ xT) {
  __shared__ __align__(16) char smem[SMEMB];
  const int bid = blockIdx.x, nb = gridDim.x, tid = threadIdx.x;
  phase_prep(bid, nb, tid, x, W, Bs, xB, xT, smem);
  gridbar(bc, 1);
  phase_sgemm(bid, nb, tid, xB, Bs, s_part, smem);
  gridbar(bc, 2);
  phase_squash(bid, nb, tid, s_part, esum, vB, out, 0, smem);
  gridbar(bc, 3);
  phase_agg(bid, nb, tid, xT, W, vB, bijT);
  gridbar(bc, 4);
  phase_rebuild(bid, nb, tid, W, bijT, Bs, esum + 16, smem);
  gridbar(bc, 5);
  phase_sgemm(bid, nb, tid, xB, Bs, s_part, smem);
  gridbar(bc, 6);
  phase_squash(bid, nb, tid, s_part, esum + 16, vB, out, 0, smem);
  gridbar(bc, 7);
  phase_agg(bid, nb, tid, xT, W, vB, bijT);
  gridbar(bc, 8);
  phase_rebuild(bid, nb, tid, W, bijT, Bs, esum + 32, smem);
  gridbar(bc, 9);
  phase_sgemm(bid, nb, tid, xB, Bs, s_part, smem);
  gridbar(bc, 10);
  phase_squash(bid, nb, tid, s_part, esum + 32, vB, out, 1, smem);
}

// ---- fallback wrappers (kernel boundaries provide the sync) ----------------
__global__ __launch_bounds__(256) void prep_k(const float* x, const float* W,
                                              short* Bs, short* xB, short* xT) {
  __shared__ __align__(16) char smem[SMEMB];
  phase_prep(blockIdx.x, gridDim.x, threadIdx.x, x, W, Bs, xB, xT, smem);
}
__global__ __launch_bounds__(256) void sgemm_k(const short* xB, const short* Bs,
                                               float* s_part) {
  __shared__ __align__(16) char smem[SMEMB];
  phase_sgemm(blockIdx.x, gridDim.x, threadIdx.x, xB, Bs, s_part, smem);
}
__global__ __launch_bounds__(256) void squash_k(const float* s_part, const float* esum_in,
                                                short* vB, float* out, int write_out) {
  __shared__ __align__(16) char smem[SMEMB];
  phase_squash(blockIdx.x, gridDim.x, threadIdx.x, s_part, esum_in, vB, out,
               write_out, smem);
}
__global__ __launch_bounds__(256) void agg_k(const short* xT, const float* W,
                                             const short* vB, float* bijT) {
  phase_agg(blockIdx.x, gridDim.x, threadIdx.x, xT, W, vB, bijT);
}
__global__ __launch_bounds__(256) void rebuild_k(const float* W, const float* bijT,
                                                 short* Bs, float* esumOut) {
  __shared__ __align__(16) char smem[SMEMB];
  phase_rebuild(blockIdx.x, gridDim.x, threadIdx.x, W, bijT, Bs, esumOut, smem);
}

// ---- launch ----------------------------------------------------------------
extern "C" void kernel_launch(void* const* d_in, const int* in_sizes, int n_in,
                              void* d_out, int out_size, void* d_ws, size_t ws_size,
                              hipStream_t stream) {
  const float* x = (const float*)d_in[0];  // [512,1152,8] fp32
  const float* W = (const float*)d_in[1];  // [1152,10,16,8] fp32
  float* out = (float*)d_out;              // [512,10,16] fp32

  float* bijT = (float*)d_ws;                          // 11520 f
  float* s_part = bijT + IO;                           // 12*512*160 f
  float* esum = s_part + (size_t)NCS * B * 160;        // 48 f (pad 64)
  int* bc = (int*)(esum + 64);                         // barrier ctr (pad 16)
  short* vB = (short*)(bc + 16);                       // 16*160*32 shorts
  short* Bs = vB + (size_t)16 * 160 * 32;              // 288*160*32 shorts
  short* xB = Bs + (size_t)NKB * 160 * 32;             // 512*9216 shorts
  short* xT = xB + (size_t)B * KD;                     // 9216*512 shorts

  static int g_nb = 0;
  if (g_nb == 0) {
    int dev = 0, ncu = 0, occ = 0;
    hipGetDevice(&dev);
    hipDeviceGetAttribute(&ncu, hipDeviceAttributeMultiprocessorCount, dev);
    hipOccupancyMaxActiveBlocksPerMultiprocessor(&occ, (const void*)mega_kernel, 256, 0);
    long cap = (long)occ * ncu;
    g_nb = cap < NBTARGET ? (int)cap : NBTARGET;
    if (g_nb < 64) g_nb = -1;  // cannot co-reside enough blocks -> fallback
  }

  init_kernel<<<48, 256, 0, stream>>>(bijT, esum, bc);

  bool coop = false;
  if (g_nb > 0) {
    void* args[] = {(void*)&x,  (void*)&W,    (void*)&out, (void*)&s_part,
                    (void*)&bijT, (void*)&esum, (void*)&bc,  (void*)&vB,
                    (void*)&Bs, (void*)&xB,   (void*)&xT};
    hipError_t e = hipLaunchCooperativeKernel((const void*)mega_kernel, dim3(g_nb),
                                              dim3(256), args, 0, stream);
    if (e == hipSuccess) coop = true;
    else g_nb = -1;  // never retry
  }
  if (!coop) {
    prep_k<<<576, 256, 0, stream>>>(x, W, Bs, xB, xT);
    sgemm_k<<<384, 256, 0, stream>>>(xB, Bs, s_part);
    squash_k<<<160, 256, 0, stream>>>(s_part, esum, vB, out, 0);
    agg_k<<<576, 256, 0, stream>>>(xT, W, vB, bijT);
    rebuild_k<<<144, 256, 0, stream>>>(W, bijT, Bs, esum + 16);
    sgemm_k<<<384, 256, 0, stream>>>(xB, Bs, s_part);
    squash_k<<<160, 256, 0, stream>>>(s_part, esum + 16, vB, out, 0);
    agg_k<<<576, 256, 0, stream>>>(xT, W, vB, bijT);
    rebuild_k<<<144, 256, 0, stream>>>(W, bijT, Bs, esum + 32);
    sgemm_k<<<384, 256, 0, stream>>>(xB, Bs, s_part);
    squash_k<<<160, 256, 0, stream>>>(s_part, esum + 32, vB, out, 1);
  }
}

// Round 13
// 171.812 us; speedup vs baseline: 2.3720x; 2.3720x over previous
//
#include <hip/hip_runtime.h>
#include <hip/hip_bf16.h>

// DigitCaps dynamic routing. Output fp32.
// R26 = R25 resubmitted verbatim (Round-12 bench was an infra failure:
// container died twice, kernel never ran). Audit: no spin-waits, no OOB,
// u64 loads 8B-aligned, shuffle groups 8-aligned, state re-init per launch.
// R25 = R20 (champion, 173.3us) + two surgical shaves:
//  1. co-XCD swizzle: mb = bid&31, cz = bid>>5 -> all 12 producers +
//     finisher of an mb share XCD mb%8 (stride-32 = 0 mod 8); xB L2-local.
//     Pure perf: finisher still uses bypass (agent atomic) loads.
//  2. finisher sums partials via 64-bit agent loads (halves the LLC-latency
//     tail); squash reduce regrouped to width-8 shuffles (80 = 8x10: groups
//     never straddle rows or o-groups).
// Chain: prep | sgemm | agg2 | sgemm | agg2 | sgemm  (6 dispatches).
#define B 512
#define IC 1152
#define QD 8
#define OD 10
#define PD 16
#define KD (IC * QD)       // 9216
#define NKB (KD / 32)      // 288 K32 blocks
#define NCS 12             // K-chunks for s GEMM; grid 32*12 = 384 blocks
#define KSTEPS 6           // 288 / (NCS*4 waves)
#define MB 32              // M-tiles (16 rows each)
#define NCB 4              // b-chunks for agreement GEMM (128 each)
#define SOP (B * OD * PD)  // 81920
#define IO (IC * OD)       // 11520
#define TPX ((B / 64) * (KD / 64))  // 8*144 = 1152 transpose tiles

typedef short bf16x8 __attribute__((ext_vector_type(8)));
typedef short bf16x4 __attribute__((ext_vector_type(4)));
typedef float f32x4 __attribute__((ext_vector_type(4)));

__device__ __forceinline__ short f2bf(float f) {
  union { float f; unsigned u; } x;
  x.f = f;
  unsigned r = x.u + 0x7FFFu + ((x.u >> 16) & 1u);  // RNE to bf16
  return (short)(r >> 16);
}

// ---------------- prep: xB + xT transpose, Bs = bf16(W), zero state ---------
__global__ __launch_bounds__(256) void prep_kernel(const float* __restrict__ x,
                                                   const float* __restrict__ W,
                                                   float* __restrict__ bijT,
                                                   int* __restrict__ ctrS,
                                                   int* __restrict__ ctrA,
                                                   float* __restrict__ esum,
                                                   short* __restrict__ Bs,
                                                   short* __restrict__ xB,
                                                   short* __restrict__ xT) {
  const int bid = blockIdx.x, tid = threadIdx.x;
  // distributed state zeroing
  {
    const int g = bid * 256 + tid;
    if (g < IO) bijT[g] = 0.f;
    const int z = g - IO;
    if (z >= 0) {
      if (z < 32) ctrS[z] = 0;
      else if (z < 192) ctrA[z - 32] = 0;
      else if (z < 240) esum[z - 192] = (z - 192 < 16) ? (float)IC : 0.f;
    }
  }
  if (bid < TPX) {
    // 64 b x 64 iq tile: read x fp32, emit xB (linear bf16) + xT (transposed)
    __shared__ short lds[64 * 72];  // [iq_loc][b_loc], pad 72
    const int bt = bid / (KD / 64), qt = bid % (KD / 64);
    const int b0 = bt * 64, c0 = qt * 64;
    const int row0 = tid >> 4, col4 = (tid & 15) * 4;
#pragma unroll
    for (int j = 0; j < 4; ++j) {
      const int row = row0 + j * 16;
      const float4 v = *(const float4*)(x + (size_t)(b0 + row) * KD + c0 + col4);
      bf16x4 ov;
      ov[0] = f2bf(v.x); ov[1] = f2bf(v.y); ov[2] = f2bf(v.z); ov[3] = f2bf(v.w);
      *(bf16x4*)(xB + (size_t)(b0 + row) * KD + c0 + col4) = ov;
      lds[(col4 + 0) * 72 + row] = ov[0];
      lds[(col4 + 1) * 72 + row] = ov[1];
      lds[(col4 + 2) * 72 + row] = ov[2];
      lds[(col4 + 3) * 72 + row] = ov[3];
    }
    __syncthreads();
    const int iq = tid & 63, seg = tid >> 6;  // 16 b per (iq,seg)
    const short* src = lds + iq * 72 + seg * 16;
    short* dst = xT + (size_t)(c0 + iq) * B + b0 + seg * 16;
    *(bf16x8*)dst = *(const bf16x8*)src;
    *(bf16x8*)(dst + 8) = *(const bf16x8*)(src + 8);
    return;
  }
  const int t = (bid - TPX) * 256 + tid;  // 0..46079
  const int kb = t / 160, n = t % 160;
  const int o = n >> 4, p = n & 15;
  short ov[32];
#pragma unroll
  for (int quad = 0; quad < 4; ++quad) {
    const int i = kb * 4 + quad;
    const float4* wp = (const float4*)(W + (((size_t)i * OD + o) * PD + p) * QD);
    const float4 w0 = wp[0], w1 = wp[1];
    ov[quad * 8 + 0] = f2bf(w0.x); ov[quad * 8 + 1] = f2bf(w0.y);
    ov[quad * 8 + 2] = f2bf(w0.z); ov[quad * 8 + 3] = f2bf(w0.w);
    ov[quad * 8 + 4] = f2bf(w1.x); ov[quad * 8 + 5] = f2bf(w1.y);
    ov[quad * 8 + 6] = f2bf(w1.z); ov[quad * 8 + 7] = f2bf(w1.w);
  }
  int4* dst = (int4*)(Bs + (size_t)t * 32);
  const int4* src = (const int4*)ov;
#pragma unroll
  for (int j = 0; j < 4; ++j) dst[j] = src[j];
}

// ---------------- sgemm: 16-row tile, 4-wave K-split, coalesced WT stores ---
// grid MB*NCS; mb = bid&31 (co-XCD per mb), cz = bid>>5. Finisher = last cz.
__global__ __launch_bounds__(256) void sgemm_kernel(const short* __restrict__ xB,
                                                    const short* __restrict__ Bs,
                                                    const float* __restrict__ esum_in,
                                                    float* __restrict__ s_part,
                                                    int* __restrict__ ctrS,
                                                    short* __restrict__ vB,
                                                    float* __restrict__ out,
                                                    int write_out) {
  __shared__ float sbuf[4][16][168];  // 43KB, +8 pad
  __shared__ int flag;
  __shared__ float einv[OD];
  const int tid = threadIdx.x;
  const int wave = tid >> 6, lane = tid & 63;
  const int ln = lane & 15, quad = lane >> 4;
  const int mb = blockIdx.x & 31, cz = blockIdx.x >> 5;  // co-XCD swizzle
  const int m0 = mb * 16;
  const int czw = cz * 4 + wave;  // 0..47 K-chunks of 6 K32-steps
  f32x4 acc[10] = {};
  const short* arow = xB + (size_t)(m0 + ln) * KD + quad * 8;
#pragma unroll
  for (int step = 0; step < KSTEPS; ++step) {
    const int kb = czw * KSTEPS + step;
    const bf16x8 af = *(const bf16x8*)(arow + (size_t)kb * 32);
    const short* bp = Bs + (size_t)kb * 5120 + ln * 32 + quad * 8;
#pragma unroll
    for (int nt = 0; nt < 10; ++nt) {
      const bf16x8 bf = *(const bf16x8*)(bp + nt * 512);
      acc[nt] = __builtin_amdgcn_mfma_f32_16x16x32_bf16(af, bf, acc[nt], 0, 0, 0);
    }
  }
  // wave partials -> LDS (C layout: row=quad*4+r, col=nt*16+ln)
#pragma unroll
  for (int nt = 0; nt < 10; ++nt)
#pragma unroll
    for (int r = 0; r < 4; ++r)
      sbuf[wave][quad * 4 + r][nt * 16 + ln] = acc[nt][r];
  __syncthreads();
  // block partial = sum of 4 waves; coalesced agent write-through stores
#pragma unroll
  for (int j = 0; j < 10; ++j) {
    const int e = tid + j * 256;  // 0..2559
    const int row = e / 160, col = e % 160;
    const float v = sbuf[0][row][col] + sbuf[1][row][col] +
                    sbuf[2][row][col] + sbuf[3][row][col];
    __hip_atomic_store(&s_part[((size_t)cz * B + m0 + row) * 160 + col], v,
                       __ATOMIC_RELAXED, __HIP_MEMORY_SCOPE_AGENT);
  }
  asm volatile("s_waitcnt vmcnt(0)" ::: "memory");  // stores at coherence point
  __syncthreads();
  if (tid == 0)
    flag = (__hip_atomic_fetch_add(&ctrS[mb], 1, __ATOMIC_RELAXED,
                                   __HIP_MEMORY_SCOPE_AGENT) == NCS - 1) ? 1 : 0;
  __syncthreads();
  if (!flag) return;
  if (tid == 0)
    __hip_atomic_store(&ctrS[mb], 0, __ATOMIC_RELAXED, __HIP_MEMORY_SCOPE_AGENT);
  if (tid < OD) einv[tid] = 1.f / esum_in[tid];  // prev-dispatch data
  __syncthreads();
  // finisher: 16 rows x 160 cols = 1280 u64 slots, 5 per thread; 8-lane
  // groups cover one (row, o) 16-col span -> width-8 shfl squash.
#pragma unroll
  for (int j = 0; j < 5; ++j) {
    const int e2 = tid + j * 256;         // 0..1279
    const int row = e2 / 80, c2p = e2 - row * 80;
    const int o = c2p >> 3;
    float sx = 0.f, sy = 0.f;
#pragma unroll
    for (int c2 = 0; c2 < NCS; ++c2) {
      const unsigned long long v = __hip_atomic_load(
          (const unsigned long long*)(s_part +
              ((size_t)c2 * B + m0 + row) * 160 + c2p * 2),
          __ATOMIC_RELAXED, __HIP_MEMORY_SCOPE_AGENT);
      union { unsigned long long u; float f[2]; } cv;
      cv.u = v;
      sx += cv.f[0]; sy += cv.f[1];
    }
    const float ei = einv[o];
    sx *= ei; sy *= ei;
    float sq = sx * sx + sy * sy;
    sq += __shfl_xor(sq, 1, 8);
    sq += __shfl_xor(sq, 2, 8);
    sq += __shfl_xor(sq, 4, 8);
    const float norm = sqrtf(sq + 1e-8f);
    const float scale = sq / ((1.f + sq) * norm);
    const int b = m0 + row, col = c2p * 2;
    if (write_out) {
      float2 val;
      val.x = sx * scale; val.y = sy * scale;
      *(float2*)(out + (size_t)b * 160 + col) = val;
    } else {
      short* vb = vB + ((size_t)(b >> 5) * 160 + col) * 32 + (b & 31);
      vb[0] = f2bf(sx * scale);
      vb[32] = f2bf(sy * scale);
    }
  }
}

// ---------------- agg2: bijT += agreement; finisher: Bs slice + esum --------
// grid (144 ig8, 4 kq). G[m=(i8q),(n=o*16+p)] = sum_b xT[iq][b]*v[b][op].
__global__ __launch_bounds__(256) void agg2_kernel(const short* __restrict__ xT,
                                                   const float* __restrict__ W,
                                                   const short* __restrict__ vB,
                                                   float* __restrict__ bijT,
                                                   short* __restrict__ Bs,
                                                   int* __restrict__ ctrA,
                                                   float* __restrict__ esumOut) {
  const int tid = threadIdx.x;
  const int ig8 = blockIdx.x, kq = blockIdx.y;
  const int mt = tid >> 6, lane = tid & 63;
  const int ln = lane & 15, quad = lane >> 4;
  f32x4 acc[10] = {};
  const short* arow = xT + (size_t)(ig8 * 64 + mt * 16 + ln) * B + kq * 128 + quad * 8;
#pragma unroll
  for (int kb = 0; kb < 4; ++kb) {
    const bf16x8 af = *(const bf16x8*)(arow + kb * 32);
    const short* bp = vB + ((size_t)(kq * 4 + kb) * 160 + ln) * 32 + quad * 8;
#pragma unroll
    for (int nt = 0; nt < 10; ++nt) {
      const bf16x8 bf = *(const bf16x8*)(bp + nt * 512);
      acc[nt] = __builtin_amdgcn_mfma_f32_16x16x32_bf16(af, bf, acc[nt], 0, 0, 0);
    }
  }
  // epilogue: contract G with W -> agreement; RETURNED atomics (ordering!)
  const int i = ig8 * 8 + mt * 2 + (quad >> 1);
  const int qb = (quad & 1) * 4;
  float rsum = 0.f;
#pragma unroll
  for (int nt = 0; nt < 10; ++nt) {
    const float4 wv = *(const float4*)(W + (((size_t)i * OD + nt) * PD + ln) * QD + qb);
    float pa = acc[nt][0] * wv.x + acc[nt][1] * wv.y + acc[nt][2] * wv.z + acc[nt][3] * wv.w;
    pa += __shfl_xor(pa, 1); pa += __shfl_xor(pa, 2); pa += __shfl_xor(pa, 4);
    pa += __shfl_xor(pa, 8); pa += __shfl_xor(pa, 16);
    if ((lane & 31) == 0)
      rsum += atomicAdd(&bijT[(size_t)nt * IC + i], pa * (1.0f / (float)B));
  }
  asm volatile("" :: "v"(rsum));
  __syncthreads();
  __shared__ int flag;
  __shared__ float eL[8][OD];
  if (tid == 0)
    flag = (__hip_atomic_fetch_add(&ctrA[ig8], 1, __ATOMIC_RELAXED,
                                   __HIP_MEMORY_SCOPE_AGENT) == NCB - 1) ? 1 : 0;
  __syncthreads();
  if (!flag) return;
  // finisher: rebuild Bs k-blocks [ig8*2, ig8*2+1] = exp(bij)*W (unnormalized)
  if (tid < 8 * OD) {
    const int il = tid / OD, o = tid - il * OD;
    const float bv = __hip_atomic_load(&bijT[(size_t)o * IC + ig8 * 8 + il],
                                       __ATOMIC_RELAXED, __HIP_MEMORY_SCOPE_AGENT);
    eL[il][o] = __expf(bv);
  }
  if (tid == 0)
    __hip_atomic_store(&ctrA[ig8], 0, __ATOMIC_RELAXED, __HIP_MEMORY_SCOPE_AGENT);
  __syncthreads();
  if (tid < OD) {  // softmax denominator contribution for this ig8's 8 i's
    float s = 0.f;
#pragma unroll
    for (int il = 0; il < 8; ++il) s += eL[il][tid];
    atomicAdd(&esumOut[tid], s);
  }
  for (int vb = tid; vb < 320; vb += 256) {
    const int kbl = vb / 160, n = vb - kbl * 160;
    const int kb = ig8 * 2 + kbl;
    const int o = n >> 4, pp = n & 15;
    short ov[32];
#pragma unroll
    for (int q4 = 0; q4 < 4; ++q4) {
      const int ii = kb * 4 + q4;
      const float ci = eL[ii - ig8 * 8][o];
      const float4* wp = (const float4*)(W + (((size_t)ii * OD + o) * PD + pp) * QD);
      const float4 w0 = wp[0], w1 = wp[1];
      ov[q4 * 8 + 0] = f2bf(ci * w0.x); ov[q4 * 8 + 1] = f2bf(ci * w0.y);
      ov[q4 * 8 + 2] = f2bf(ci * w0.z); ov[q4 * 8 + 3] = f2bf(ci * w0.w);
      ov[q4 * 8 + 4] = f2bf(ci * w1.x); ov[q4 * 8 + 5] = f2bf(ci * w1.y);
      ov[q4 * 8 + 6] = f2bf(ci * w1.z); ov[q4 * 8 + 7] = f2bf(ci * w1.w);
    }
    int4* dst = (int4*)(Bs + (size_t)(kb * 160 + n) * 32);
    const int4* src = (const int4*)ov;
#pragma unroll
    for (int j = 0; j < 4; ++j) dst[j] = src[j];
  }
}

// ---------------- launch: 6 dispatches --------------------------------------

extern "C" void kernel_launch(void* const* d_in, const int* in_sizes, int n_in,
                              void* d_out, int out_size, void* d_ws, size_t ws_size,
                              hipStream_t stream) {
  const float* x = (const float*)d_in[0];  // [512,1152,8] fp32
  const float* W = (const float*)d_in[1];  // [1152,10,16,8] fp32
  float* out = (float*)d_out;              // [512,10,16] fp32

  // workspace ~25 MB; every buffer written before read per call
  float* bijT = (float*)d_ws;                          // 11520 f
  float* s_part = bijT + IO;                           // 12*512*160 f
  int* ctrS = (int*)(s_part + (size_t)NCS * B * 160);  // 32 i
  int* ctrA = ctrS + 32;                               // 160 i
  float* esum = (float*)(ctrA + 160);                  // 48 f (pad 64)
  short* vB = (short*)(esum + 64);                     // 16*160*32 shorts
  short* Bs = vB + (size_t)16 * 160 * 32;              // 288*160*32 shorts
  short* xB = Bs + (size_t)NKB * 160 * 32;             // 512*9216 shorts
  short* xT = xB + (size_t)B * KD;                     // 9216*512 shorts

  const dim3 agrid(144, NCB);

  prep_kernel<<<TPX + 180, 256, 0, stream>>>(x, W, bijT, ctrS, ctrA, esum,
                                             Bs, xB, xT);
  // iter 1 (esum slot0 pre-set to IC by prep)
  sgemm_kernel<<<MB * NCS, 256, 0, stream>>>(xB, Bs, esum, s_part, ctrS, vB, out, 0);
  agg2_kernel<<<agrid, 256, 0, stream>>>(xT, W, vB, bijT, Bs, ctrA, esum + 16);
  // iter 2
  sgemm_kernel<<<MB * NCS, 256, 0, stream>>>(xB, Bs, esum + 16, s_part, ctrS, vB, out, 0);
  agg2_kernel<<<agrid, 256, 0, stream>>>(xT, W, vB, bijT, Bs, ctrA, esum + 32);
  // iter 3
  sgemm_kernel<<<MB * NCS, 256, 0, stream>>>(xB, Bs, esum + 32, s_part, ctrS, vB, out, 1);
}